// Round 4
// baseline (338.069 us; speedup 1.0000x reference)
//
#include <hip/hip_runtime.h>

#define NNODES 50000
#define NEDGES 800000
#define DIM 96
#define LLDIM 64
#define NRELS 3            // metapath relations 0,1,2
#define SCAN_N (NRELS * NNODES)

// ---------------- CSR build ----------------

__global__ void hist_kernel(const int* __restrict__ ei, const int* __restrict__ et,
                            int* __restrict__ deg) {
    int e = blockIdx.x * 256 + threadIdx.x;
    if (e >= NEDGES) return;
    int r = et[e];
    if (r < NRELS) atomicAdd(&deg[r * NNODES + ei[e]], 1);
}

__global__ void scan1_kernel(const int* __restrict__ in, int* __restrict__ out,
                             int* __restrict__ partials, int n) {
    __shared__ int sdata[256];
    int tid = threadIdx.x;
    int base = blockIdx.x * 1024 + tid * 4;
    int v0 = (base + 0 < n) ? in[base + 0] : 0;
    int v1 = (base + 1 < n) ? in[base + 1] : 0;
    int v2 = (base + 2 < n) ? in[base + 2] : 0;
    int v3 = (base + 3 < n) ? in[base + 3] : 0;
    int tsum = v0 + v1 + v2 + v3;
    sdata[tid] = tsum;
    __syncthreads();
    for (int off = 1; off < 256; off <<= 1) {
        int x = sdata[tid];
        int y = (tid >= off) ? sdata[tid - off] : 0;
        __syncthreads();
        sdata[tid] = x + y;
        __syncthreads();
    }
    int excl = sdata[tid] - tsum;
    if (tid == 255) partials[blockIdx.x] = sdata[255];
    if (base + 0 < n) out[base + 0] = excl;
    excl += v0;
    if (base + 1 < n) out[base + 1] = excl;
    excl += v1;
    if (base + 2 < n) out[base + 2] = excl;
    excl += v2;
    if (base + 3 < n) out[base + 3] = excl;
}

__global__ void scan2_kernel(int* __restrict__ partials, int nb) {
    __shared__ int sdata[256];
    int tid = threadIdx.x;
    int v = (tid < nb) ? partials[tid] : 0;
    sdata[tid] = v;
    __syncthreads();
    for (int off = 1; off < 256; off <<= 1) {
        int x = sdata[tid];
        int y = (tid >= off) ? sdata[tid - off] : 0;
        __syncthreads();
        sdata[tid] = x + y;
        __syncthreads();
    }
    partials[tid] = sdata[tid] - v;   // exclusive
}

// writes final row_start AND initializes the fill cursor (saves a d2d copy)
__global__ void scan3_kernel(int* __restrict__ rs, int* __restrict__ cursor,
                             const int* __restrict__ partials, int n) {
    int idx = blockIdx.x * 256 + threadIdx.x;
    if (idx < n) {
        int v = rs[idx] + partials[idx >> 10];
        rs[idx] = v;
        cursor[idx] = v;
    }
}

// cursor pre-initialized to row_start; after fill it holds row ends.
__global__ void fill_kernel(const int* __restrict__ ei, const int* __restrict__ et,
                            int* __restrict__ cursor, int* __restrict__ col) {
    int e = blockIdx.x * 256 + threadIdx.x;
    if (e >= NEDGES) return;
    int r = et[e];
    if (r < NRELS) {
        int pos = atomicAdd(&cursor[r * NNODES + ei[e]], 1);
        col[pos] = ei[NEDGES + e];
    }
}

// ---------------- gather: agg[n] = mean_{d in N(n)} h[d]  (float4, 2-deep ILP) ----------------
// 32-lane group per node; lanes 0..23 each own one float4 of the 96-float row.

__global__ __launch_bounds__(256) void gather_kernel(
    const float* __restrict__ h, const int* __restrict__ rs,
    const int* __restrict__ re, const int* __restrict__ col,
    float* __restrict__ agg) {
    int node = blockIdx.x * 8 + (threadIdx.x >> 5);
    if (node >= NNODES) return;
    int l = threadIdx.x & 31;
    if (l >= 24) return;
    int s = rs[node];
    int e = re[node];
    float4 acc = make_float4(0.f, 0.f, 0.f, 0.f);
    int i = s;
    for (; i + 1 < e; i += 2) {
        const float4* r0 = (const float4*)(h + (size_t)col[i] * DIM);
        const float4* r1 = (const float4*)(h + (size_t)col[i + 1] * DIM);
        float4 u = r0[l];
        float4 v = r1[l];
        acc.x += u.x + v.x; acc.y += u.y + v.y;
        acc.z += u.z + v.z; acc.w += u.w + v.w;
    }
    if (i < e) {
        float4 u = ((const float4*)(h + (size_t)col[i] * DIM))[l];
        acc.x += u.x; acc.y += u.y; acc.z += u.z; acc.w += u.w;
    }
    float scl = 1.0f / fmaxf((float)(e - s), 1.0f);
    acc.x *= scl; acc.y *= scl; acc.z *= scl; acc.w *= scl;
    ((float4*)(agg + (size_t)node * DIM))[l] = acc;
}

// ---------------- layer GEMM: out = relu(agg@W + h@R + b) ----------------
// Block: 64 nodes x 96 cols, 384 threads. Two passes (agg@W, h@R), K=96 each.
// A staged ONCE per pass (transposed [k][node]); W double-buffered in 24-k chunks
// so global W loads overlap compute. acc 4 nodes x 4 cols per thread.

#define WPAD 100   // 16B-aligned (100*4=400), 100%32=4 spreads banks

__global__ __launch_bounds__(384) void layer_kernel(
    const float* __restrict__ h, const float* __restrict__ agg,
    const float* __restrict__ W, const float* __restrict__ R,
    const float* __restrict__ b, float* __restrict__ out) {
    __shared__ __align__(16) float Alds[96][68];        // 26.1 KB
    __shared__ __align__(16) float Wlds[2][24][WPAD];   // 19.2 KB
    int tid = threadIdx.x;
    int n0 = blockIdx.x * 64;
    int nq = tid & 15;       // node quad
    int coct = tid >> 4;     // col quad index 0..23

    float acc[4][4];
#pragma unroll
    for (int j = 0; j < 4; ++j)
#pragma unroll
        for (int c = 0; c < 4; ++c) acc[j][c] = 0.0f;

    for (int pass = 0; pass < 2; ++pass) {
        const float* A = pass ? h : agg;
        const float* B = pass ? R : W;
        __syncthreads();   // previous pass's compute done before Alds overwrite
        // stage A transposed: 64 rows x 24 float4
        for (int idx = tid; idx < 64 * 24; idx += 384) {
            int row = idx & 63;
            int kq = idx >> 6;
            int rn = n0 + row;
            if (rn >= NNODES) rn = NNODES - 1;
            float4 v = *(const float4*)(A + (size_t)rn * DIM + kq * 4);
            Alds[kq * 4 + 0][row] = v.x;
            Alds[kq * 4 + 1][row] = v.y;
            Alds[kq * 4 + 2][row] = v.z;
            Alds[kq * 4 + 3][row] = v.w;
        }
        // stage W chunk 0 into buffer 0
        for (int idx = tid; idx < 576; idx += 384) {
            int kr = idx / 24;
            int cq = idx % 24;
            *(float4*)&Wlds[0][kr][cq * 4] = *(const float4*)(B + (size_t)kr * DIM + cq * 4);
        }
        __syncthreads();
        for (int chunk = 0; chunk < 4; ++chunk) {
            int buf = chunk & 1;
            if (chunk < 3) {   // prefetch next chunk into other buffer
                for (int idx = tid; idx < 576; idx += 384) {
                    int kr = idx / 24;
                    int cq = idx % 24;
                    *(float4*)&Wlds[buf ^ 1][kr][cq * 4] =
                        *(const float4*)(B + (size_t)((chunk + 1) * 24 + kr) * DIM + cq * 4);
                }
            }
            int kbase = chunk * 24;
#pragma unroll 4
            for (int k = 0; k < 24; ++k) {
                float4 a4 = *(float4*)&Alds[kbase + k][nq * 4];
                float4 w4 = *(float4*)&Wlds[buf][k][coct * 4];
                acc[0][0] += a4.x * w4.x; acc[0][1] += a4.x * w4.y;
                acc[0][2] += a4.x * w4.z; acc[0][3] += a4.x * w4.w;
                acc[1][0] += a4.y * w4.x; acc[1][1] += a4.y * w4.y;
                acc[1][2] += a4.y * w4.z; acc[1][3] += a4.y * w4.w;
                acc[2][0] += a4.z * w4.x; acc[2][1] += a4.z * w4.y;
                acc[2][2] += a4.z * w4.z; acc[2][3] += a4.z * w4.w;
                acc[3][0] += a4.w * w4.x; acc[3][1] += a4.w * w4.y;
                acc[3][2] += a4.w * w4.z; acc[3][3] += a4.w * w4.w;
            }
            __syncthreads();
        }
    }

    float4 bv = *(const float4*)(b + coct * 4);
    int nbase = n0 + nq * 4;
#pragma unroll
    for (int j = 0; j < 4; ++j) {
        int n = nbase + j;
        if (n < NNODES) {
            float4 r;
            r.x = fmaxf(acc[j][0] + bv.x, 0.0f);
            r.y = fmaxf(acc[j][1] + bv.y, 0.0f);
            r.z = fmaxf(acc[j][2] + bv.z, 0.0f);
            r.w = fmaxf(acc[j][3] + bv.w, 0.0f);
            *(float4*)(out + (size_t)n * DIM + coct * 4) = r;
        }
    }
}

// ---------------- final linear: out = h @ lin_w + lin_b ----------------
// Block: 64 nodes x 64 cols, 256 threads. Full K staged once, 1 compute phase.

__global__ __launch_bounds__(256) void final_kernel(
    const float* __restrict__ h, const float* __restrict__ LW,
    const float* __restrict__ LB, float* __restrict__ out) {
    __shared__ __align__(16) float Alds[96][68];     // 26.1 KB
    __shared__ __align__(16) float Wlds[96][68];     // 26.1 KB (64 cols + pad)
    int tid = threadIdx.x;
    int q = tid & 15;        // col quad
    int nb = tid >> 4;       // node quad
    int n0 = blockIdx.x * 64;

    // stage A transposed
    for (int idx = tid; idx < 64 * 24; idx += 256) {
        int row = idx & 63;
        int kq = idx >> 6;
        int rn = n0 + row;
        if (rn >= NNODES) rn = NNODES - 1;
        float4 v = *(const float4*)(h + (size_t)rn * DIM + kq * 4);
        Alds[kq * 4 + 0][row] = v.x;
        Alds[kq * 4 + 1][row] = v.y;
        Alds[kq * 4 + 2][row] = v.z;
        Alds[kq * 4 + 3][row] = v.w;
    }
    // stage W: 96 rows x 16 float4
    for (int idx = tid; idx < 96 * 16; idx += 256) {
        int kr = idx >> 4;
        int cq = idx & 15;
        *(float4*)&Wlds[kr][cq * 4] = *(const float4*)(LW + (size_t)kr * LLDIM + cq * 4);
    }
    __syncthreads();

    float acc[4][4];
#pragma unroll
    for (int j = 0; j < 4; ++j)
#pragma unroll
        for (int c = 0; c < 4; ++c) acc[j][c] = 0.0f;

#pragma unroll 4
    for (int k = 0; k < 96; ++k) {
        float4 a4 = *(float4*)&Alds[k][nb * 4];
        float4 w4 = *(float4*)&Wlds[k][q * 4];
        acc[0][0] += a4.x * w4.x; acc[0][1] += a4.x * w4.y;
        acc[0][2] += a4.x * w4.z; acc[0][3] += a4.x * w4.w;
        acc[1][0] += a4.y * w4.x; acc[1][1] += a4.y * w4.y;
        acc[1][2] += a4.y * w4.z; acc[1][3] += a4.y * w4.w;
        acc[2][0] += a4.z * w4.x; acc[2][1] += a4.z * w4.y;
        acc[2][2] += a4.z * w4.z; acc[2][3] += a4.z * w4.w;
        acc[3][0] += a4.w * w4.x; acc[3][1] += a4.w * w4.y;
        acc[3][2] += a4.w * w4.z; acc[3][3] += a4.w * w4.w;
    }

    float4 bv = *(const float4*)(LB + q * 4);
    int nbase = n0 + nb * 4;
#pragma unroll
    for (int j = 0; j < 4; ++j) {
        int n = nbase + j;
        if (n < NNODES) {
            float4 r;
            r.x = acc[j][0] + bv.x;
            r.y = acc[j][1] + bv.y;
            r.z = acc[j][2] + bv.z;
            r.w = acc[j][3] + bv.w;
            *(float4*)(out + (size_t)n * LLDIM + q * 4) = r;
        }
    }
}

extern "C" void kernel_launch(void* const* d_in, const int* in_sizes, int n_in,
                              void* d_out, int out_size, void* d_ws, size_t ws_size,
                              hipStream_t stream) {
    const float* x     = (const float*)d_in[0];
    const int*   ei    = (const int*)d_in[1];
    const int*   et    = (const int*)d_in[2];
    const float* w1    = (const float*)d_in[3];
    const float* root1 = (const float*)d_in[4];
    const float* b1    = (const float*)d_in[5];
    const float* w2    = (const float*)d_in[6];
    const float* root2 = (const float*)d_in[7];
    const float* b2    = (const float*)d_in[8];
    const float* lin_w = (const float*)d_in[9];
    const float* lin_b = (const float*)d_in[10];

    float* bufA = (float*)d_ws;                      // N*96
    float* bufB = bufA + (size_t)NNODES * DIM;       // N*96
    float* agg  = bufB + (size_t)NNODES * DIM;       // N*96
    int* deg       = (int*)(agg + (size_t)NNODES * DIM);
    int* row_start = deg + SCAN_N;
    int* row_end   = row_start + SCAN_N;             // fill cursor -> row ends
    int* col       = row_end + SCAN_N;               // up to NEDGES
    int* partials  = col + NEDGES;                   // 256

    const int edge_blocks = (NEDGES + 255) / 256;
    const int scan_blocks = (SCAN_N + 1023) / 1024;  // 147
    const int node_tiles  = (NNODES + 63) / 64;      // 782
    const int gath_blocks = (NNODES + 7) / 8;        // 6250

    // ---- CSR build (edge structure identical for all 3 layers) ----
    hipMemsetAsync(deg, 0, SCAN_N * sizeof(int), stream);
    hist_kernel<<<edge_blocks, 256, 0, stream>>>(ei, et, deg);
    scan1_kernel<<<scan_blocks, 256, 0, stream>>>(deg, row_start, partials, SCAN_N);
    scan2_kernel<<<1, 256, 0, stream>>>(partials, scan_blocks);
    scan3_kernel<<<(SCAN_N + 255) / 256, 256, 0, stream>>>(row_start, row_end, partials, SCAN_N);
    fill_kernel<<<edge_blocks, 256, 0, stream>>>(ei, et, row_end, col);

    // ---- Layer 0: rel 0, w1[0], root1, b1 :  x -> bufA ----
    gather_kernel<<<gath_blocks, 256, 0, stream>>>(
        x, row_start + 0 * NNODES, row_end + 0 * NNODES, col, agg);
    layer_kernel<<<node_tiles, 384, 0, stream>>>(x, agg, w1, root1, b1, bufA);

    // ---- Layer 1: rel 1, w2[1], root2, b2 :  bufA -> bufB ----
    gather_kernel<<<gath_blocks, 256, 0, stream>>>(
        bufA, row_start + 1 * NNODES, row_end + 1 * NNODES, col, agg);
    layer_kernel<<<node_tiles, 384, 0, stream>>>(bufA, agg, w2 + (size_t)1 * DIM * DIM,
                                                 root2, b2, bufB);

    // ---- Layer 2: rel 2, w2[2], root2, b2 :  bufB -> bufA ----
    gather_kernel<<<gath_blocks, 256, 0, stream>>>(
        bufB, row_start + 2 * NNODES, row_end + 2 * NNODES, col, agg);
    layer_kernel<<<node_tiles, 384, 0, stream>>>(bufB, agg, w2 + (size_t)2 * DIM * DIM,
                                                 root2, b2, bufA);

    // ---- Final linear: bufA -> d_out ----
    final_kernel<<<node_tiles, 256, 0, stream>>>(bufA, lin_w, lin_b, (float*)d_out);
}